// Round 6
// baseline (214.795 us; speedup 1.0000x reference)
//
#include <hip/hip_runtime.h>
#include <hip/hip_bf16.h>

#define B_   4
#define S_   4096
#define D_   1024
#define M_   (B_ * S_)   // 16384
#define K_   1024
#define BK   32
#define NT   (K_ / BK)   // 32

typedef __attribute__((ext_vector_type(4))) float f32x4;
typedef __attribute__((ext_vector_type(8))) short bf16x8;
typedef unsigned short ushort_t;
typedef unsigned int uint_t;

#define SCHEDB __builtin_amdgcn_sched_barrier(0)
#define MFMA16(a, b, c) __builtin_amdgcn_mfma_f32_16x16x32_bf16(a, b, c, 0, 0, 0)

__device__ inline ushort_t f2bf(float f) {
    union { float f; unsigned u; } v; v.f = f;
    unsigned r = v.u + 0x7fffu + ((v.u >> 16) & 1u);
    return (ushort_t)(r >> 16);
}
__device__ inline float bf2f(ushort_t s) {
    union { unsigned u; float f; } v; v.u = ((unsigned)s) << 16; return v.f;
}

// ---------------- convert x (fp32) -> bf16, 8 elems/thread ----------------
__global__ void convert_x_kernel(const float4* __restrict__ x, ushort_t* __restrict__ xb) {
    int i = blockIdx.x * 256 + threadIdx.x;
    float4 a = x[2 * i], b = x[2 * i + 1];
    union { ushort_t s[8]; uint4 v; } u;
    u.s[0] = f2bf(a.x); u.s[1] = f2bf(a.y); u.s[2] = f2bf(a.z); u.s[3] = f2bf(a.w);
    u.s[4] = f2bf(b.x); u.s[5] = f2bf(b.y); u.s[6] = f2bf(b.z); u.s[7] = f2bf(b.w);
    ((uint4*)xb)[i] = u.v;
}

// ---- W_in fp32 [1024][2048] -> WinT bf16 [2048][1024], gate/hidden interleaved by 16 cols ----
__global__ void transpose_win_kernel(const float* __restrict__ W, ushort_t* __restrict__ WT) {
    __shared__ float tile[32][33];
    int tx = threadIdx.x, ty = threadIdx.y;
    int n0 = blockIdx.x * 32, k0 = blockIdx.y * 32;
    int ci = (n0 >> 1) + (tx & 15) + ((tx & 16) ? 1024 : 0);
    tile[ty][tx] = W[(long)(k0 + ty) * 2048 + ci];
    __syncthreads();
    WT[(long)(n0 + ty) * 1024 + k0 + tx] = f2bf(tile[tx][ty]);
}

// ---- W_out fp32 [1024][1024] -> WoT bf16 [1024][1024] ----
__global__ void transpose_wo_kernel(const float* __restrict__ W, ushort_t* __restrict__ WT) {
    __shared__ float tile[32][33];
    int tx = threadIdx.x, ty = threadIdx.y;
    int n0 = blockIdx.x * 32, k0 = blockIdx.y * 32;
    tile[ty][tx] = W[(long)(k0 + ty) * 1024 + n0 + tx];
    __syncthreads();
    WT[(long)(n0 + ty) * 1024 + k0 + tx] = f2bf(tile[tx][ty]);
}

// ---------------- stage one 256x32 bf16 tile pair (A 16KB + B 16KB) ----------------
// LDS dest linear [256 rows][64B]; row's 4x16B slots: LDS slot s holds global k-slot (s-row)&3.
// Per wave: 2 loads for A + 2 for B; lane l covers row (w*2+j)*16 + (l>>2), slot l&3.
__device__ inline void stage4(const char* ga, const char* gb, char* buf,
                              int so0, int so1, int w) {
    int ld = w * 2048;
    __builtin_amdgcn_global_load_lds((const __attribute__((address_space(1))) void*)(ga + so0),
                                     (__attribute__((address_space(3))) void*)(buf + ld), 16, 0, 0);
    __builtin_amdgcn_global_load_lds((const __attribute__((address_space(1))) void*)(ga + so1),
                                     (__attribute__((address_space(3))) void*)(buf + ld + 1024), 16, 0, 0);
    __builtin_amdgcn_global_load_lds((const __attribute__((address_space(1))) void*)(gb + so0),
                                     (__attribute__((address_space(3))) void*)(buf + 16384 + ld), 16, 0, 0);
    __builtin_amdgcn_global_load_lds((const __attribute__((address_space(1))) void*)(gb + so1),
                                     (__attribute__((address_space(3))) void*)(buf + 16384 + ld + 1024), 16, 0, 0);
}

// ---------------- 256x256 GEMM, BK=32, 8 waves, 4-buffer rotation, counted vmcnt(8) ----------------
template<int NBN, int GATE>
__global__ __launch_bounds__(512, 2) void gemm8_kernel(
    const ushort_t* __restrict__ A, const ushort_t* __restrict__ Bm,
    const float* __restrict__ bias, void* __restrict__ outp)
{
    extern __shared__ char smem[];
    const int tid = threadIdx.x;
    const int l = tid & 63, w = tid >> 6;
    const int wm = w >> 2, wn = w & 3;
    const int lrow = l & 15, kgrp = l >> 4;

    const int nwg = gridDim.x;
    const int cpx = nwg >> 3;
    const int bid = blockIdx.x;
    const int wg = (bid & 7) * cpx + (bid >> 3);
    const long m0 = (long)(wg / NBN) * 256;
    const long n0 = (long)(wg % NBN) * 256;

    const char* gA = (const char*)A + m0 * 2048;
    const char* gB = (const char*)Bm + n0 * 2048;

    // staging source offsets: row = (w*2+j)*16 + (l>>2); gslot = ((l&3) - row) & 3
    const int r0 = (w * 2 + 0) * 16 + (l >> 2);
    const int r1 = (w * 2 + 1) * 16 + (l >> 2);
    const int soff0 = r0 * 2048 + ((((l & 3) - r0) & 3) << 4);
    const int soff1 = r1 * 2048 + ((((l & 3) - r1) & 3) << 4);

    // fragment ds_read offsets: row*64 + ((kgrp+row)&3)*16 ; row&3 == lrow&3
    const int fsw = (((kgrp + lrow) & 3) << 4);
    int a_off[8], b_off[4];
#pragma unroll
    for (int fm = 0; fm < 8; ++fm) a_off[fm] = (wm * 128 + fm * 16 + lrow) * 64 + fsw;
#pragma unroll
    for (int fn = 0; fn < 4; ++fn) b_off[fn] = 16384 + (wn * 64 + fn * 16 + lrow) * 64 + fsw;

    f32x4 acc[8][4];
#pragma unroll
    for (int i = 0; i < 8; ++i)
#pragma unroll
        for (int j = 0; j < 4; ++j) acc[i][j] = f32x4{0.f, 0.f, 0.f, 0.f};

    // prologue: stage tiles 0,1,2 into bufs 0,1,2; wait tile 0 (8 newer loads float)
    stage4(gA, gB, smem, soff0, soff1, w);
    stage4(gA + 64, gB + 64, smem + 32768, soff0, soff1, w);
    stage4(gA + 128, gB + 128, smem + 65536, soff0, soff1, w);
    asm volatile("s_waitcnt vmcnt(8)" ::: "memory");
    __builtin_amdgcn_s_barrier();

    for (int tb = 0; tb < NT / 4; ++tb) {
#pragma unroll
        for (int q = 0; q < 4; ++q) {
            const int t = tb * 4 + q;
            char* cbuf = smem + (q << 15);
            char* sbuf = smem + (((q + 3) & 3) << 15);

            // stage tile t+3 into buffer (t+3)&3 (its last readers finished at tile t-1)
            if (t + 3 < NT) stage4(gA + (t + 3) * 64, gB + (t + 3) * 64, sbuf, soff0, soff1, w);

            // read this tile's 12 fragments
            bf16x8 af[8], bf[4];
#pragma unroll
            for (int fm = 0; fm < 8; ++fm) af[fm] = *(const bf16x8*)(cbuf + a_off[fm]);
#pragma unroll
            for (int fn = 0; fn < 4; ++fn) bf[fn] = *(const bf16x8*)(cbuf + b_off[fn]);

            asm volatile("s_waitcnt lgkmcnt(0)" ::: "memory");
            SCHEDB;
            __builtin_amdgcn_s_setprio(1);
#pragma unroll
            for (int fm = 0; fm < 8; ++fm)
#pragma unroll
                for (int fn = 0; fn < 4; ++fn)
                    acc[fm][fn] = MFMA16(af[fm], bf[fn], acc[fm][fn]);
            __builtin_amdgcn_s_setprio(0);
            SCHEDB;

            // publish tile t+1: counted wait (8 newer loads stay in flight), never 0 until tail
            if (t < NT - 1) {
                if (t <= NT - 4)      asm volatile("s_waitcnt vmcnt(8)" ::: "memory");
                else if (t == NT - 3) asm volatile("s_waitcnt vmcnt(4)" ::: "memory");
                else                  asm volatile("s_waitcnt vmcnt(0)" ::: "memory");
                __builtin_amdgcn_s_barrier();
            }
        }
    }

    // ---------------- epilogue ----------------
    const long row0 = m0 + wm * 128 + kgrp * 4;
    if (GATE) {
        ushort_t* g = (ushort_t*)outp;
#pragma unroll
        for (int fm = 0; fm < 8; ++fm) {
#pragma unroll
            for (int fp = 0; fp < 2; ++fp) {
                int c = (int)(n0 >> 1) + wn * 32 + fp * 16 + lrow;
                float bg = bias[c], bh = bias[1024 + c];
#pragma unroll
                for (int r = 0; r < 4; ++r) {
                    long rr = row0 + fm * 16 + r;
                    float gate = acc[fm][fp * 2][r] + bg;
                    float hid  = acc[fm][fp * 2 + 1][r] + bh;
                    float sg = 1.0f / (1.0f + expf(-gate));
                    float sh = 1.0f / (1.0f + expf(-hid));
                    g[rr * 1024 + c] = f2bf(sg * hid * sh);
                }
            }
        }
    } else {
        float* o = (float*)outp;
#pragma unroll
        for (int fm = 0; fm < 8; ++fm)
#pragma unroll
            for (int fn = 0; fn < 4; ++fn) {
                int c = (int)n0 + wn * 64 + fn * 16 + lrow;
                float bo = bias[c];
#pragma unroll
                for (int r = 0; r < 4; ++r) {
                    long rr = row0 + fm * 16 + r;
                    o[rr * 1024 + c] = acc[fm][fn][r] + bo;
                }
            }
    }
}

// ---------------- EMA scan: chunked, HALO=96, 2 channels/thread ----------------
__global__ void scan_kernel(const ushort_t* __restrict__ g, ushort_t* __restrict__ h) {
    int idx = blockIdx.x * 256 + threadIdx.x;
    int b = idx >> 9, d = (idx & 511) * 2;
    int chunk = blockIdx.y;
    const ushort_t* gb = g + (long)b * S_ * 1024 + d;
    ushort_t* hb = h + (long)b * S_ * 1024 + d;
    float h0 = 0.f, h1 = 0.f;
    int t0 = chunk * 256;
    int tw = t0 - 96; if (tw < 0) tw = 0;
    for (int t = tw; t < t0; ++t) {
        uint_t v = *(const uint_t*)(gb + (long)t * 1024);
        h0 = 0.9f * h0 + 0.1f * bf2f((ushort_t)(v & 0xffffu));
        h1 = 0.9f * h1 + 0.1f * bf2f((ushort_t)(v >> 16));
    }
    for (int t = t0; t < t0 + 256; ++t) {
        uint_t v = *(const uint_t*)(gb + (long)t * 1024);
        h0 = 0.9f * h0 + 0.1f * bf2f((ushort_t)(v & 0xffffu));
        h1 = 0.9f * h1 + 0.1f * bf2f((ushort_t)(v >> 16));
        *(uint_t*)(hb + (long)t * 1024) = (((uint_t)f2bf(h1)) << 16) | (uint_t)f2bf(h0);
    }
}

extern "C" void kernel_launch(void* const* d_in, const int* in_sizes, int n_in,
                              void* d_out, int out_size, void* d_ws, size_t ws_size,
                              hipStream_t stream) {
    const float* x     = (const float*)d_in[0];
    const float* W_in  = (const float*)d_in[1];
    const float* b_in  = (const float*)d_in[2];
    const float* W_out = (const float*)d_in[3];
    const float* b_out = (const float*)d_in[4];
    float* outp = (float*)d_out;

    char* ws = (char*)d_ws;
    ushort_t* xb   = (ushort_t*)ws;                        // 32 MB: x bf16, later reused for h bf16
    ushort_t* winT = (ushort_t*)(ws + 33554432);           // 4 MB
    ushort_t* woT  = (ushort_t*)(ws + 33554432 + 4194304); // 2 MB
    ushort_t* gbuf = (ushort_t*)(ws + 33554432 + 6291456); // 32 MB

    hipFuncSetAttribute((const void*)&gemm8_kernel<8, 1>, hipFuncAttributeMaxDynamicSharedMemorySize, 131072);
    hipFuncSetAttribute((const void*)&gemm8_kernel<4, 0>, hipFuncAttributeMaxDynamicSharedMemorySize, 131072);

    convert_x_kernel<<<8192, 256, 0, stream>>>((const float4*)x, xb);
    transpose_win_kernel<<<dim3(64, 32), dim3(32, 32), 0, stream>>>(W_in, winT);
    transpose_wo_kernel<<<dim3(32, 32), dim3(32, 32), 0, stream>>>(W_out, woT);
    gemm8_kernel<8, 1><<<512, 512, 131072, stream>>>(xb, winT, b_in, (void*)gbuf);
    scan_kernel<<<dim3(8, 16), 256, 0, stream>>>(gbuf, xb);
    gemm8_kernel<4, 0><<<256, 512, 131072, stream>>>(xb, woT, b_out, (void*)outp);
}